// Round 1
// baseline (165.231 us; speedup 1.0000x reference)
//
#include <hip/hip_runtime.h>
#include <math.h>

#define N_NODES 8192
#define D_FEAT  512
#define DEG     16
#define E_EDGES (N_NODES * DEG)
#define FEAT_W  576      // 544 used (8*(64+4)) + 32 zero-pad for K%64==0
#define FEAT_USED 544
#define OUT_W   512
#define QKV_W   1664     // 512 q | 512 k | 512 v | 24 qv | 104 pad  (13*128)
#define BF_ROWS 1792     // Bfuse padded to 7*256 for 256-wide N tiles

typedef unsigned short u16;
typedef __attribute__((ext_vector_type(8))) short short8;   // 8 bf16 for MFMA
typedef __attribute__((ext_vector_type(8))) unsigned short us8;
typedef __attribute__((ext_vector_type(4))) float f32x4;

// ---- bf16 helpers (RNE) ----------------------------------------------------
__device__ __forceinline__ u16 f2bf(float f) {
    union { float f; unsigned u; } c; c.f = f;
    unsigned u = c.u;
    unsigned r = u + 0x7FFFu + ((u >> 16) & 1u);
    return (u16)(r >> 16);
}
__device__ __forceinline__ float bf2f(u16 h) {
    union { unsigned u; float f; } c; c.u = ((unsigned)h) << 16;
    return c.f;
}

// ---- async global->LDS 16B (lds dest = wave-uniform base + lane*16) --------
__device__ __forceinline__ void async16(const void* g, void* l) {
    __builtin_amdgcn_global_load_lds(
        (const __attribute__((address_space(1))) void*)g,
        (__attribute__((address_space(3))) void*)l, 16, 0, 0);
}

// ---------------------------------------------------------------------------
// qkv GEMM, 8-phase-style pipelined (T2+T3+T4+T5):
//   qkv[8192, 1664] = xh[8192,512] * Bfuse[1792,512]^T  (cols >=1560 unused)
// BM=BN=256, 8 waves (2M x 4N), per-wave 128x64 output, BK=32 with a 4-deep
// LDS ring (4x16KB A + 4x16KB B = 128 KiB) -> prefetch distance 3 K-steps,
// counted s_waitcnt vmcnt(8) at K-step boundaries (never a drain in the main
// loop; epilogue drains 8->4->0). 2 phases/K-step x 16 MFMA, setprio around
// the MFMA cluster, raw s_barrier (no vmcnt drain), XOR-swizzled LDS
// (inverse-swizzled global source + swizzled ds_read_b128; 16-lane 2-way).
// Grid 224 = 8 XCD x 28 (bijective swizzle), 1 block/CU, one dispatch round.
// ---------------------------------------------------------------------------
__global__ __launch_bounds__(512, 2) void gemm_qkv(
    const u16* __restrict__ xh, const u16* __restrict__ Bfuse,
    u16* __restrict__ qkv)
{
    __shared__ u16 ldsA[4][256 * 32];   // 64 KB
    __shared__ u16 ldsB[4][256 * 32];   // 64 KB

    const int tid  = threadIdx.x;
    const int wid  = tid >> 6;          // 0..7
    const int lane = tid & 63;
    const int wm   = wid >> 2;          // 0..1  (M-half of the tile)
    const int wn   = wid & 3;           // 0..3  (64-col N slice)
    const int lrow = lane & 15;
    const int quad = lane >> 4;

    const int flat = blockIdx.x;        // 0..223
    const int wg   = (flat & 7) * 28 + (flat >> 3);   // contiguous per XCD
    const int bm   = (wg / 7) * 256;
    const int bn   = (wg % 7) * 256;

    const u16* gA = xh    + (size_t)bm * 512;
    const u16* gB = Bfuse + (size_t)bn * 512;

    // staging geometry: K-step tile is 256 rows x 32 cols = 1024 chunks of
    // 8 bf16; thread handles chunks c0=tid, c1=512+tid. LDS dest is linear
    // (chunk order); global source k-segment is XOR-swizzled so that the
    // swizzled ds_read below sees consistent data (both-sides rule).
    const int c0 = tid,       r0 = c0 >> 2;
    const int c1 = 512 + tid, r1 = c1 >> 2;
    const int o0 = (((c0 & 3) ^ ((r0 >> 1) & 3)) << 3);
    const int o1 = (((c1 & 3) ^ ((r1 >> 1) & 3)) << 3);

#define STAGE_A(s) do {                                                      \
        u16* _d = &ldsA[(s) & 3][0];                                         \
        async16(gA + (size_t)r0 * 512 + (s) * 32 + o0, _d + c0 * 8);         \
        async16(gA + (size_t)r1 * 512 + (s) * 32 + o1, _d + c1 * 8);         \
    } while (0)
#define STAGE_B(s) do {                                                      \
        u16* _d = &ldsB[(s) & 3][0];                                         \
        async16(gB + (size_t)r0 * 512 + (s) * 32 + o0, _d + c0 * 8);         \
        async16(gB + (size_t)r1 * 512 + (s) * 32 + o1, _d + c1 * 8);         \
    } while (0)

    f32x4 acc[8][4];
    #pragma unroll
    for (int i = 0; i < 8; ++i)
        #pragma unroll
        for (int j = 0; j < 4; ++j) {
            f32x4 z = {0.f, 0.f, 0.f, 0.f};
            acc[i][j] = z;
        }

    // prologue: stage K-steps 0,1,2 (12 load instrs/thread); wait the oldest
    // 4 (K-step 0) to land, then barrier for cross-wave visibility.
    STAGE_A(0); STAGE_B(0);
    STAGE_A(1); STAGE_B(1);
    STAGE_A(2); STAGE_B(2);
    asm volatile("s_waitcnt vmcnt(8)" ::: "memory");
    __builtin_amdgcn_s_barrier();

    #pragma unroll
    for (int s = 0; s < 16; ++s) {              // 16 K-steps of 32
        const int b = s & 3;
        const u16* sa = &ldsA[b][0];
        const u16* sb = &ldsB[b][0];
        short8 av[4], bv[4], av2[4];

        // -------- phase 0: C rows wm*128 + [0,64) --------------------------
        #pragma unroll
        for (int m = 0; m < 4; ++m) {
            const int row = wm * 128 + m * 16 + lrow;
            av[m] = *(const short8*)&sa[row * 32 + ((quad ^ ((row >> 1) & 3)) << 3)];
        }
        #pragma unroll
        for (int n = 0; n < 4; ++n) {
            const int row = wn * 64 + n * 16 + lrow;
            bv[n] = *(const short8*)&sb[row * 32 + ((quad ^ ((row >> 1) & 3)) << 3)];
        }
        if (s < 13) STAGE_A(s + 3);
        __builtin_amdgcn_s_barrier();
        asm volatile("s_waitcnt lgkmcnt(0)" ::: "memory");
        __builtin_amdgcn_sched_barrier(0);
        __builtin_amdgcn_s_setprio(1);
        #pragma unroll
        for (int m = 0; m < 4; ++m)
            #pragma unroll
            for (int n = 0; n < 4; ++n)
                acc[m][n] = __builtin_amdgcn_mfma_f32_16x16x32_bf16(
                    av[m], bv[n], acc[m][n], 0, 0, 0);
        __builtin_amdgcn_s_setprio(0);
        __builtin_amdgcn_s_barrier();

        // -------- phase 1: C rows wm*128 + [64,128) ------------------------
        #pragma unroll
        for (int m = 0; m < 4; ++m) {
            const int row = wm * 128 + 64 + m * 16 + lrow;
            av2[m] = *(const short8*)&sa[row * 32 + ((quad ^ ((row >> 1) & 3)) << 3)];
        }
        if (s < 13) STAGE_B(s + 3);
        __builtin_amdgcn_s_barrier();
        asm volatile("s_waitcnt lgkmcnt(0)" ::: "memory");
        __builtin_amdgcn_sched_barrier(0);
        __builtin_amdgcn_s_setprio(1);
        #pragma unroll
        for (int m = 0; m < 4; ++m)
            #pragma unroll
            for (int n = 0; n < 4; ++n)
                acc[4 + m][n] = __builtin_amdgcn_mfma_f32_16x16x32_bf16(
                    av2[m], bv[n], acc[4 + m][n], 0, 0, 0);
        __builtin_amdgcn_s_setprio(0);
        // K-step boundary: ensure K-step s+1 has LANDED before any wave's
        // next-group ds_reads. Counted in steady state (leaves s+2, s+3 =
        // 8 loads in flight); epilogue drains 8 -> 4 -> 0.
        if (s < 13)       asm volatile("s_waitcnt vmcnt(8)" ::: "memory");
        else if (s == 13) asm volatile("s_waitcnt vmcnt(4)" ::: "memory");
        else if (s == 14) asm volatile("s_waitcnt vmcnt(0)" ::: "memory");
        __builtin_amdgcn_s_barrier();
    }
#undef STAGE_A
#undef STAGE_B

    // epilogue: C/D layout col = lane&15, row = quad*4 + r. Skip pad cols.
    #pragma unroll
    for (int np = 0; np < 4; ++np) {
        const int col = bn + wn * 64 + np * 16 + lrow;
        if (col < 1560) {
            #pragma unroll
            for (int mp = 0; mp < 8; ++mp)
                #pragma unroll
                for (int r = 0; r < 4; ++r) {
                    const int row = bm + wm * 128 + mp * 16 + quad * 4 + r;
                    qkv[(size_t)row * QKV_W + col] = f2bf(acc[mp][np][r]);
                }
        }
    }
}

// ---------------------------------------------------------------------------
// Out GEMM: out[8192,512] = feat[8192,576] * Woth[512,576]^T + bout.
// 64x128 tiles, BK=64, grid 512 = 2 blocks/CU. R11-proven.
// ---------------------------------------------------------------------------
__global__ __launch_bounds__(256) void gemm_out(
    const u16* __restrict__ feat, const u16* __restrict__ Woth,
    const float* __restrict__ bout, float* __restrict__ out)
{
    __shared__ u16 smem[64 * 64 + 128 * 64];   // 24 KB
    u16* sA = smem;
    u16* sB = smem + 64 * 64;

    const int tid = threadIdx.x;
    const int flat = blockIdx.x;
    const int xcd = flat & 7;
    const int rr  = flat >> 3;                  // 0..63
    const int bm  = (xcd + 8 * (rr / 4)) * 64;
    const int bn  = (rr % 4) * 128;

    const int wave = tid >> 6;
    const int lane = tid & 63;
    const int wr   = (wave >> 1) * 32;
    const int wc   = (wave & 1) * 64;
    const int lrow = lane & 15;
    const int quad = lane >> 4;

    f32x4 acc[2][4];
    #pragma unroll
    for (int i = 0; i < 2; ++i)
        #pragma unroll
        for (int j = 0; j < 4; ++j) {
            f32x4 z = {0.f, 0.f, 0.f, 0.f};
            acc[i][j] = z;
        }

    for (int k0 = 0; k0 < FEAT_W; k0 += 64) {
        #pragma unroll
        for (int i = 0; i < 2; ++i) {             // A: 512 chunks
            const int lin = i * 256 + tid;
            const int row = lin >> 3;
            const int seg = ((lin & 7) ^ (row & 7)) << 3;
            async16(feat + (size_t)(bm + row) * FEAT_W + k0 + seg, sA + (lin << 3));
        }
        #pragma unroll
        for (int i = 0; i < 4; ++i) {             // B: 1024 chunks
            const int lin = i * 256 + tid;
            const int row = lin >> 3;
            const int seg = ((lin & 7) ^ (row & 7)) << 3;
            async16(Woth + (size_t)(bn + row) * FEAT_W + k0 + seg, sB + (lin << 3));
        }
        __syncthreads();

        #pragma unroll
        for (int ko = 0; ko < 64; ko += 32) {
            const int cbase = ko >> 3;
            short8 a_h[2], b_h[4];
            #pragma unroll
            for (int t = 0; t < 2; ++t) {
                const int ra = wr + t * 16 + lrow;
                a_h[t] = *(const short8*)&sA[ra * 64 + (((cbase + quad) ^ (ra & 7)) << 3)];
            }
            #pragma unroll
            for (int t = 0; t < 4; ++t) {
                const int rb = wc + t * 16 + lrow;
                b_h[t] = *(const short8*)&sB[rb * 64 + (((cbase + quad) ^ (rb & 7)) << 3)];
            }
            #pragma unroll
            for (int mt = 0; mt < 2; ++mt)
                #pragma unroll
                for (int nt = 0; nt < 4; ++nt)
                    acc[mt][nt] = __builtin_amdgcn_mfma_f32_16x16x32_bf16(
                        a_h[mt], b_h[nt], acc[mt][nt], 0, 0, 0);
        }
        __syncthreads();
    }

    #pragma unroll
    for (int nt = 0; nt < 4; ++nt) {
        const int col = bn + wc + nt * 16 + lrow;
        const float bb = bout[col];
        #pragma unroll
        for (int mt = 0; mt < 2; ++mt)
            #pragma unroll
            for (int r = 0; r < 4; ++r) {
                const int row = bm + wr + mt * 16 + quad * 4 + r;
                out[(size_t)row * OUT_W + col] = acc[mt][nt][r] + bb;
            }
    }
}

// ---------------------------------------------------------------------------
// Fused prep: x->bf16, Bfuse (1792 rows incl. qv + zero pad), Woth.
// ---------------------------------------------------------------------------
__global__ __launch_bounds__(256) void prep_kernel(
    const float* __restrict__ x,
    const float* __restrict__ Wq, const float* __restrict__ Wk,
    const float* __restrict__ Wv, const float* __restrict__ Wqv,
    const float* __restrict__ Wout,
    u16* __restrict__ xh, u16* __restrict__ B, u16* __restrict__ Woth)
{
    const int b = blockIdx.x;
    const int tid = threadIdx.x;
    if (b < 4096) {
        const int i = b * 256 + tid;
        const float4 v = ((const float4*)x)[i];
        ushort4 h;
        h.x = f2bf(v.x); h.y = f2bf(v.y); h.z = f2bf(v.z); h.w = f2bf(v.w);
        ((ushort4*)xh)[i] = h;
    } else if (b < 4992) {
        const int idx = (b - 4096) * 256 + tid;      // < 229376 = 1792*128
        const int row = idx >> 7;                    // 0..1791
        const int c4  = idx & 127;
        float4 v = make_float4(0.f, 0.f, 0.f, 0.f);
        float scale = 1.f;
        if (row < 512) {
            v = *(const float4*)(Wq + (size_t)row * 512 + c4 * 4);
            scale = 0.125f;                          // 1/sqrt(64) folded into Wq
        } else if (row < 1024) {
            v = *(const float4*)(Wk + (size_t)(row - 512) * 512 + c4 * 4);
        } else if (row < 1536) {
            v = *(const float4*)(Wv + (size_t)(row - 1024) * 512 + c4 * 4);
        } else if (row < 1560) {
            v = *(const float4*)(Wqv + (size_t)(row - 1536) * 512 + c4 * 4);
        }
        ushort4 h;
        h.x = f2bf(v.x * scale); h.y = f2bf(v.y * scale);
        h.z = f2bf(v.z * scale); h.w = f2bf(v.w * scale);
        ((ushort4*)B)[idx] = h;
    } else {
        const int i = (b - 4992) * 256 + tid;        // < 73728 exact
        const int row = i / (FEAT_W / 4);            // /144
        const int c4  = i % (FEAT_W / 4);
        float4 v = make_float4(0.f, 0.f, 0.f, 0.f);
        if (c4 < FEAT_USED / 4)
            v = *(const float4*)(Wout + (size_t)row * FEAT_USED + c4 * 4);
        ushort4 h;
        h.x = f2bf(v.x); h.y = f2bf(v.y); h.z = f2bf(v.z); h.w = f2bf(v.w);
        ((ushort4*)Woth)[i] = h;
    }
}

// ---------------------------------------------------------------------------
// Edge stage: TWO WAVES PER NODE (wave owns 8 edges, all 512 dims).
// Block = 256 threads = 4 waves = 2 nodes. lane = h*8+sub; hoff = lane*8.
// Pass 1: each wave computes 8 logits (coalesced k-row gathers).
// LDS exchange of per-head logits (64 fp32/node) -> full 16-way softmax
// replicated in both waves. Pass 2: each wave re-gathers its 8 v rows and
// accumulates partial y/dx/dy/dz/aid; wave 0 publishes partials via LDS;
// wave 1 combines and writes feat. ~6 KB LDS/block -> occupancy VGPR-bound.
// ---------------------------------------------------------------------------
__global__ __launch_bounds__(256) void edge_kernel(
    const u16* __restrict__ qkv,        // [N, 1664] bf16
    const int* __restrict__ col_index, const int* __restrict__ to_col,
    const float* __restrict__ att_bias, const float* __restrict__ dist,
    const float* __restrict__ pos, const float* __restrict__ col_pos,
    u16* __restrict__ feat)             // [N, 576] bf16 (544 used)
{
    __shared__ float sLog[2][2][8][8];  // [node][wave][head][edge]  2 KB
    __shared__ float sY[2][512];        // partial y exchange        4 KB
    __shared__ float sV[2][8][4];       // dx,dy,dz,aid per head     256 B

    const int wave4 = threadIdx.x >> 6;   // 0..3
    const int nb = wave4 >> 1;            // node within block
    const int w  = wave4 & 1;             // wave within node
    const int lane = threadIdx.x & 63;
    const int n = blockIdx.x * 2 + nb;
    const int h = lane >> 3;
    const int sub = lane & 7;
    const int hoff = lane * 8;            // == h*64 + sub*8

    const size_t qbase = (size_t)n * QKV_W;

    // q fragment (8 dims), fp32
    float qf[8];
    {
        const us8 qu = *(const us8*)(qkv + qbase + hoff);
        #pragma unroll
        for (int i = 0; i < 8; ++i) qf[i] = bf2f(qu[i]);
    }
    // qv (3 per head) via wave shuffle from the 24 bf16 at col 1536
    float qv0, qv1, qv2;
    {
        const float qvl = bf2f(qkv[qbase + 1536 + (lane < 24 ? lane : 0)]);
        qv0 = __shfl(qvl, h * 3 + 0);
        qv1 = __shfl(qvl, h * 3 + 1);
        qv2 = __shfl(qvl, h * 3 + 2);
    }
    const float px = pos[3 * n + 0], py = pos[3 * n + 1], pz = pos[3 * n + 2];

    // per-edge metadata for THIS wave's 8 edges, held in lanes 0..7
    // (all 8-lane groups hold duplicates)
    const int j8 = lane & 7;
    const int e0 = n * DEG + w * 8 + j8;
    const int c_l  = col_index[e0];
    const int cc_l = to_col[c_l];
    const float d_l = dist[e0];
    const float invd_l = (d_l == 0.f) ? 0.f : (1.f / d_l);
    const float rx_l = col_pos[3 * c_l + 0] - px;
    const float ry_l = col_pos[3 * c_l + 1] - py;
    const float rz_l = col_pos[3 * c_l + 2] - pz;

    // bias: lane (h,sub) holds bias for head h, edge w*8+sub
    const float b_own = att_bias[(size_t)h * E_EDGES + n * DEG + w * 8 + sub];

    // ---- pass 1: logits for my 8 edges -------------------------------------
    float logit[8];
    #pragma unroll
    for (int j = 0; j < 8; ++j) {
        const int cc = __shfl(cc_l, j);
        const us8 ku = *(const us8*)(qkv + (size_t)cc * QKV_W + 512 + hoff);
        float dot = 0.f;
        #pragma unroll
        for (int i = 0; i < 8; ++i) dot += qf[i] * bf2f(ku[i]);
        dot += __shfl_xor(dot, 1, 8);
        dot += __shfl_xor(dot, 2, 8);
        dot += __shfl_xor(dot, 4, 8);
        const float invd = __shfl(invd_l, j);
        const float ang = qv0 * __shfl(rx_l, j) + qv1 * __shfl(ry_l, j)
                        + qv2 * __shfl(rz_l, j);
        const float bj = __shfl(b_own, j, 8);   // lane h*8+j of this group
        logit[j] = dot + bj + ang * invd;
    }

    // ---- exchange logits, softmax over all 16 ------------------------------
    if (sub == 0) {
        #pragma unroll
        for (int j = 0; j < 8; ++j) sLog[nb][w][h][j] = logit[j];
    }
    __syncthreads();
    float lo[8];
    #pragma unroll
    for (int j = 0; j < 8; ++j) lo[j] = sLog[nb][1 - w][h][j];

    float m = logit[0];
    #pragma unroll
    for (int j = 1; j < 8; ++j) m = fmaxf(m, logit[j]);
    #pragma unroll
    for (int j = 0; j < 8; ++j) m = fmaxf(m, lo[j]);
    float s = 0.f;
    #pragma unroll
    for (int j = 0; j < 8; ++j) { logit[j] = __expf(logit[j] - m); s += logit[j]; }
    #pragma unroll
    for (int j = 0; j < 8; ++j) s += __expf(lo[j] - m);
    const float inv_s = 1.f / s;

    // ---- pass 2: weighted accumulation over my 8 edges ---------------------
    float y[8] = {0.f, 0.f, 0.f, 0.f, 0.f, 0.f, 0.f, 0.f};
    float dx = 0.f, dy = 0.f, dz = 0.f, aid = 0.f;
    #pragma unroll
    for (int j = 0; j < 8; ++j) {
        const float a = logit[j] * inv_s;
        const int cc = __shfl(cc_l, j);
        const us8 vu = *(const us8*)(qkv + (size_t)cc * QKV_W + 1024 + hoff);
        #pragma unroll
        for (int i = 0; i < 8; ++i) y[i] += a * bf2f(vu[i]);
        const float na = a * __shfl(invd_l, j);
        dx += na * __shfl(rx_l, j);      // dst_vec - src_vec == sum na*rel
        dy += na * __shfl(ry_l, j);
        dz += na * __shfl(rz_l, j);
        aid += na;
    }

    // ---- combine the two waves' partials -----------------------------------
    if (w == 0) {
        #pragma unroll
        for (int i = 0; i < 8; ++i) sY[nb][hoff + i] = y[i];
        if (sub == 0) {
            sV[nb][h][0] = dx; sV[nb][h][1] = dy;
            sV[nb][h][2] = dz; sV[nb][h][3] = aid;
        }
    }
    __syncthreads();
    if (w == 1) {
        #pragma unroll
        for (int i = 0; i < 8; ++i) y[i] += sY[nb][hoff + i];

        u16* f = feat + (size_t)n * FEAT_W + h * 68;
        ushort4 o0, o1;
        o0.x = f2bf(y[0]); o0.y = f2bf(y[1]); o0.z = f2bf(y[2]); o0.w = f2bf(y[3]);
        o1.x = f2bf(y[4]); o1.y = f2bf(y[5]); o1.z = f2bf(y[6]); o1.w = f2bf(y[7]);
        *(ushort4*)(f + sub * 8 + 0) = o0;
        *(ushort4*)(f + sub * 8 + 4) = o1;
        if (sub == 0) {
            dx += sV[nb][h][0]; dy += sV[nb][h][1];
            dz += sV[nb][h][2]; aid += sV[nb][h][3];
            const float nrm = sqrtf(dx * dx + dy * dy + dz * dz);
            const float rn = 1.f / fmaxf(nrm, 1e-12f);
            ushort4 ex;
            ex.x = f2bf(dx * rn); ex.y = f2bf(dy * rn);
            ex.z = f2bf(dz * rn); ex.w = f2bf(aid);
            *(ushort4*)(f + 64) = ex;
        }
    }
}

// ---------------------------------------------------------------------------
extern "C" void kernel_launch(void* const* d_in, const int* in_sizes, int n_in,
                              void* d_out, int out_size, void* d_ws, size_t ws_size,
                              hipStream_t stream)
{
    const float* x         = (const float*)d_in[0];
    const int*   col_index = (const int*)d_in[2];
    const int*   to_col    = (const int*)d_in[3];
    const float* att_bias  = (const float*)d_in[4];
    const float* dist      = (const float*)d_in[5];
    const float* pos       = (const float*)d_in[6];
    const float* col_pos   = (const float*)d_in[7];
    const float* Wq        = (const float*)d_in[8];
    const float* Wqv       = (const float*)d_in[9];
    const float* Wk        = (const float*)d_in[10];
    const float* Wv        = (const float*)d_in[11];
    const float* Wout      = (const float*)d_in[12];
    const float* bout      = (const float*)d_in[13];
    float* out = (float*)d_out;

    // Workspace layout (bytes), total ~47.5 MB
    char* ws = (char*)d_ws;
    u16* qkv   = (u16*)(ws + 0);           // [8192,1664] bf16  27,262,976
    u16* xh    = (u16*)(ws + 27262976);    // [8192,512]  bf16   8,388,608
    u16* Bfuse = (u16*)(ws + 35651584);    // [1792,512]  bf16   1,835,008
    u16* Woth  = (u16*)(ws + 37486592);    // [512,576]   bf16     589,824
    u16* feat  = (u16*)(ws + 38076416);    // [8192,576]  bf16   9,437,184

    dim3 blk(256);

    // 0) prep: x->bf16, Bfuse (incl. qv rows + zero pad to 1792), Woth
    hipLaunchKernelGGL(prep_kernel, dim3(5280), blk, 0, stream,
                       x, Wq, Wk, Wv, Wqv, Wout, xh, Bfuse, Woth);

    // 1) qkv = xh * Bfuse^T  (224 blocks of 512 thr, pipelined 256x256)
    hipLaunchKernelGGL(gemm_qkv, dim3(224), dim3(512), 0, stream,
                       xh, Bfuse, qkv);

    // 2) edge: 2 waves per node, LDS logit/partial exchange
    hipLaunchKernelGGL(edge_kernel, dim3(N_NODES / 2), blk, 0, stream,
                       qkv, col_index, to_col, att_bias, dist, pos, col_pos, feat);

    // 3) out = feat * Woth^T + bout  (64x128 tiles, grid 512 = 2/CU)
    hipLaunchKernelGGL(gemm_out, dim3(512), blk, 0, stream,
                       feat, Woth, bout, out);
}